// Round 1
// baseline (745.776 us; speedup 1.0000x reference)
//
#include <hip/hip_runtime.h>

#define B_ 64
#define A_ 128
#define M_ 8
#define D_ 384
#define O0_ 256
#define O2_ 192
#define O4_ 160

typedef float f32x4 __attribute__((ext_vector_type(4)));
typedef _Float16 f16x8 __attribute__((ext_vector_type(8)));
typedef _Float16 f16x4 __attribute__((ext_vector_type(4)));

__device__ __forceinline__ float celu_f(float x) {
    // F.celu(x, 0.1) = x>0 ? x : 0.1*(exp(x/0.1)-1)
    return x > 0.f ? x : 0.1f * (__expf(x * 10.f) - 1.f);
}

__device__ __forceinline__ f32x4 zero4() {
    f32x4 v; v[0] = 0.f; v[1] = 0.f; v[2] = 0.f; v[3] = 0.f; return v;
}

// Generic MFMA layer: X_out[b][o] = celu(W[o][:] . X_in[b][:] + bias[o])
// X_in: LDS fp16 [64][K], 16B-chunk swizzled (chunk ^ (b&7)).
// X_out: LDS fp16 [64][OPITCH]; swizzled if SWZ_OUT else plain.
template<int K, int O, int OPITCH, bool SWZ_OUT>
__device__ __forceinline__ void layer_mfma(const float* __restrict__ W,
                                           const float* __restrict__ bias,
                                           const _Float16* Xin, _Float16* Xout,
                                           int wave, int col, int quad)
{
    constexpr int KSTEPS = K / 32;
    constexpr int OTILES = O / 16;
    for (int ot = wave; ot < OTILES; ot += 4) {
        const float* wrow = W + (size_t)(ot * 16 + col) * K + quad * 8;
        f32x4 acc[4];
        #pragma unroll
        for (int nt = 0; nt < 4; ++nt) acc[nt] = zero4();
        #pragma unroll
        for (int ks = 0; ks < KSTEPS; ++ks) {
            f32x4 wlo = *(const f32x4*)(wrow + ks * 32);
            f32x4 whi = *(const f32x4*)(wrow + ks * 32 + 4);
            f16x8 afr;
            afr[0] = (_Float16)wlo[0]; afr[1] = (_Float16)wlo[1];
            afr[2] = (_Float16)wlo[2]; afr[3] = (_Float16)wlo[3];
            afr[4] = (_Float16)whi[0]; afr[5] = (_Float16)whi[1];
            afr[6] = (_Float16)whi[2]; afr[7] = (_Float16)whi[3];
            #pragma unroll
            for (int nt = 0; nt < 4; ++nt) {
                const int b = nt * 16 + col;
                const int c = ks * 4 + quad;
                const f16x8 bfr = *(const f16x8*)(Xin + b * K + ((c ^ (b & 7)) * 8));
                acc[nt] = __builtin_amdgcn_mfma_f32_16x16x32_f16(afr, bfr, acc[nt], 0, 0, 0);
            }
        }
        // epilogue: bias + celu, transposed store to Xout[b][o]
        const f32x4 bias4 = *(const f32x4*)(bias + ot * 16 + quad * 4);
        const int o0 = ot * 16 + quad * 4;
        #pragma unroll
        for (int nt = 0; nt < 4; ++nt) {
            const int b = nt * 16 + col;
            f16x4 h;
            #pragma unroll
            for (int r = 0; r < 4; ++r) h[r] = (_Float16)celu_f(acc[nt][r] + bias4[r]);
            if (SWZ_OUT) {
                const int c = o0 >> 3;
                *(f16x4*)(Xout + b * OPITCH + ((c ^ (b & 7)) * 8) + (o0 & 7)) = h;
            } else {
                *(f16x4*)(Xout + b * OPITCH + o0) = h;
            }
        }
    }
}

__global__ __launch_bounds__(256, 2) void nn_kernel(
    const float* __restrict__ aev,
    const float* __restrict__ w0, const float* __restrict__ b0,
    const float* __restrict__ w2, const float* __restrict__ b2,
    const float* __restrict__ w4, const float* __restrict__ b4,
    const float* __restrict__ w6, const float* __restrict__ b6,
    float* __restrict__ out)
{
    // LDS plan (bytes):
    //   bufStage: [0, 24576)        64 x 192 fp16, swizzled (aev k-chunk)
    //   X0      : [24576, 57344)    64 x 256 fp16, swizzled
    //   X2      : [0, 24576)        64 x 192 fp16, swizzled   (bufStage dead)
    //   X4      : [24576, 45568)    64 x 164 fp16, plain      (X0 dead)
    //   part    : [45568, 46592)    256 fp32
    __shared__ __align__(16) unsigned char smem_raw[57344];
    _Float16* const lds = (_Float16*)smem_raw;

    const int tid  = threadIdx.x;
    const int wave = tid >> 6;
    const int lane = tid & 63;
    const int col  = lane & 15;
    const int quad = lane >> 4;

    const int a  = blockIdx.x >> 3;
    const int m  = blockIdx.x & 7;
    const int am = a * 8 + m;

    const float* w0p = w0 + (size_t)am * O0_ * D_;
    const float* b0p = b0 + am * O0_;
    const float* w2p = w2 + (size_t)am * O2_ * O0_;
    const float* b2p = b2 + am * O2_;
    const float* w4p = w4 + (size_t)am * O4_ * O2_;
    const float* b4p = b4 + am * O4_;
    const float* w6p = w6 + am * O4_;
    const float  b6v = b6[am];

    _Float16* bufStage = lds;                 // 64 x 192
    _Float16* X0 = lds + 12288;               // 64 x 256 (byte off 24576)
    _Float16* X2 = lds;                       // 64 x 192
    _Float16* X4 = lds + 12288;               // 64 x 164 plain
    float* part = (float*)(smem_raw + 45568);

    // ---------------- Layer 0: 384 -> 256, aev staged in two 192-K chunks ----
    f32x4 acc0[4][4];
    #pragma unroll
    for (int i = 0; i < 4; ++i)
        #pragma unroll
        for (int nt = 0; nt < 4; ++nt) acc0[i][nt] = zero4();

    #pragma unroll
    for (int kc = 0; kc < 2; ++kc) {
        if (kc) __syncthreads();  // all reads of previous chunk done
        // cooperative stage: 64 rows x 24 chunks of 8 fp32 -> fp16 swizzled
        #pragma unroll
        for (int it = 0; it < 6; ++it) {
            const int idx = tid + it * 256;
            const int b = idx / 24;
            const int c = idx % 24;
            const float* src = aev + ((size_t)b * A_ + a) * D_ + kc * 192 + c * 8;
            f32x4 lo = *(const f32x4*)src;
            f32x4 hi = *(const f32x4*)(src + 4);
            f16x8 h;
            h[0] = (_Float16)lo[0]; h[1] = (_Float16)lo[1];
            h[2] = (_Float16)lo[2]; h[3] = (_Float16)lo[3];
            h[4] = (_Float16)hi[0]; h[5] = (_Float16)hi[1];
            h[6] = (_Float16)hi[2]; h[7] = (_Float16)hi[3];
            *(f16x8*)(bufStage + b * 192 + ((c ^ (b & 7)) * 8)) = h;
        }
        __syncthreads();
        #pragma unroll
        for (int i = 0; i < 4; ++i) {
            const int ot = wave + i * 4;
            const float* wrow = w0p + (size_t)(ot * 16 + col) * D_ + kc * 192 + quad * 8;
            #pragma unroll
            for (int ks = 0; ks < 6; ++ks) {
                f32x4 wlo = *(const f32x4*)(wrow + ks * 32);
                f32x4 whi = *(const f32x4*)(wrow + ks * 32 + 4);
                f16x8 afr;
                afr[0] = (_Float16)wlo[0]; afr[1] = (_Float16)wlo[1];
                afr[2] = (_Float16)wlo[2]; afr[3] = (_Float16)wlo[3];
                afr[4] = (_Float16)whi[0]; afr[5] = (_Float16)whi[1];
                afr[6] = (_Float16)whi[2]; afr[7] = (_Float16)whi[3];
                #pragma unroll
                for (int nt = 0; nt < 4; ++nt) {
                    const int b = nt * 16 + col;
                    const int c = ks * 4 + quad;
                    const f16x8 bfr = *(const f16x8*)(bufStage + b * 192 + ((c ^ (b & 7)) * 8));
                    acc0[i][nt] = __builtin_amdgcn_mfma_f32_16x16x32_f16(afr, bfr, acc0[i][nt], 0, 0, 0);
                }
            }
        }
    }
    // L0 epilogue -> X0 (pitch 256, swizzled). X0 region untouched so far.
    #pragma unroll
    for (int i = 0; i < 4; ++i) {
        const int ot = wave + i * 4;
        const f32x4 bias4 = *(const f32x4*)(b0p + ot * 16 + quad * 4);
        const int o0 = ot * 16 + quad * 4;
        #pragma unroll
        for (int nt = 0; nt < 4; ++nt) {
            const int b = nt * 16 + col;
            f16x4 h;
            #pragma unroll
            for (int r = 0; r < 4; ++r) h[r] = (_Float16)celu_f(acc0[i][nt][r] + bias4[r]);
            const int c = o0 >> 3;
            *(f16x4*)(X0 + b * 256 + ((c ^ (b & 7)) * 8) + (o0 & 7)) = h;
        }
    }
    __syncthreads();

    // ---------------- Layer 2: 256 -> 192 ----------------
    layer_mfma<256, 192, 192, true>(w2p, b2p, X0, X2, wave, col, quad);
    __syncthreads();

    // ---------------- Layer 4: 192 -> 160 (plain X4, pitch 164) -------------
    layer_mfma<192, 160, 164, false>(w4p, b4p, X2, X4, wave, col, quad);
    __syncthreads();

    // ---------------- Layer 6: 160 -> 1, VALU dot ----------------
    {
        const int b  = tid & 63;
        const int pt = tid >> 6;
        const _Float16* xrow = X4 + b * 164 + pt * 40;
        const float* wseg = w6p + pt * 40;
        float s = 0.f;
        #pragma unroll
        for (int j = 0; j < 10; ++j) {
            f32x4 wv = *(const f32x4*)(wseg + j * 4);
            f16x4 xv = *(const f16x4*)(xrow + j * 4);
            s += wv[0] * (float)xv[0] + wv[1] * (float)xv[1] +
                 wv[2] * (float)xv[2] + wv[3] * (float)xv[3];
        }
        part[tid] = s;
    }
    __syncthreads();
    if (tid < 64) {
        const float x6 = part[tid] + part[tid + 64] + part[tid + 128] + part[tid + 192] + b6v;
        atomicAdd(out + B_ * A_ + tid, x6 * 0.125f);  // /M
    }
}

__global__ void init_out_kernel(const int* __restrict__ species, float* __restrict__ out) {
    const int i = blockIdx.x * 256 + threadIdx.x;
    if (i < B_ * A_) out[i] = (float)species[i];
    if (i < B_) out[B_ * A_ + i] = 0.f;
}

extern "C" void kernel_launch(void* const* d_in, const int* in_sizes, int n_in,
                              void* d_out, int out_size, void* d_ws, size_t ws_size,
                              hipStream_t stream) {
    const int*   species = (const int*)d_in[0];
    const float* aev = (const float*)d_in[1];
    const float* w0  = (const float*)d_in[2];
    const float* b0  = (const float*)d_in[3];
    const float* w2  = (const float*)d_in[4];
    const float* b2  = (const float*)d_in[5];
    const float* w4  = (const float*)d_in[6];
    const float* b4  = (const float*)d_in[7];
    const float* w6  = (const float*)d_in[8];
    const float* b6  = (const float*)d_in[9];
    float* out = (float*)d_out;

    hipLaunchKernelGGL(init_out_kernel, dim3(32), dim3(256), 0, stream, species, out);
    hipLaunchKernelGGL(nn_kernel, dim3(A_ * M_), dim3(256), 0, stream,
                       aev, w0, b0, w2, b2, w4, b4, w6, b6, out);
}